// Round 2
// baseline (1117.109 us; speedup 1.0000x reference)
//
#include <hip/hip_runtime.h>
#include <hip/hip_bf16.h>

typedef __hip_bfloat16 bf16;

__device__ __forceinline__ float b2f(bf16 v){ return __bfloat162float(v); }
__device__ __forceinline__ bf16 f2b(float v){ return __float2bfloat16(v); }
__device__ __forceinline__ float softplus_f(float x){ return (x > 15.f) ? x : __logf(1.f + __expf(x)); }
__device__ __forceinline__ float sigmoid_f(float x){ return 1.f / (1.f + __expf(-x)); }

// ---------------- embedding: fea[n,d] = sum_k A[n,k] * W_emb[d,k] ----------------
__global__ __launch_bounds__(256) void k_embed(const float* __restrict__ A, const float* __restrict__ W,
                                               float* __restrict__ fea){
  __shared__ float Wl[92][64];
  __shared__ float Al[64][92];
  int t = threadIdx.x;
  int base = blockIdx.x * 64;
  for (int i = t; i < 92*64; i += 256){ int d = i / 92, k = i - d*92; Wl[k][d] = W[d*92 + k]; }
  for (int i = t; i < 64*92; i += 256){ int a = i / 92, k = i - a*92; Al[a][k] = A[(size_t)(base+a)*92 + k]; }
  __syncthreads();
  int d = t & 63, slot = t >> 6;
  for (int a = slot; a < 64; a += 4){
    float acc = 0.f;
    #pragma unroll 4
    for (int k = 0; k < 92; k++) acc += Al[a][k] * Wl[k][d];
    fea[(size_t)(base+a)*64 + d] = acc;
  }
}

// ---------------- P[n, c] = fea[n,:] . W_self/W_nbr columns ----------------
// c<128: P_self = fea @ W[:, :64].T ; c>=128: P_nbr = fea @ W[:, 64:128].T
__global__ __launch_bounds__(256) void k_proj(const float* __restrict__ fea, const float* __restrict__ W,
                                              float* __restrict__ P){
  __shared__ float Fl[64][64];
  int t = threadIdx.x, base = blockIdx.x * 64;
  int c = t, cc = c & 127;
  const float* wrow = W + (size_t)cc*169 + ((c < 128) ? 0 : 64);
  float wreg[64];
  #pragma unroll
  for (int d = 0; d < 64; d++) wreg[d] = wrow[d];
  for (int i = t; i < 4096; i += 256){ int a = i >> 6, d = i & 63; Fl[a][d] = fea[(size_t)(base+a)*64 + d]; }
  __syncthreads();
  for (int a = 0; a < 64; a++){
    float acc = 0.f;
    #pragma unroll
    for (int db = 0; db < 16; db++){
      float4 fv = *(const float4*)&Fl[a][db*4];
      acc += fv.x*wreg[db*4] + fv.y*wreg[db*4+1] + fv.z*wreg[db*4+2] + fv.w*wreg[db*4+3];
    }
    P[(size_t)(base+a)*256 + c] = acc;
  }
}

// ---------------- gated[n,m,c] = P_self[n,c] + P_nbr[idx[n,m],c] + nbr_fea[n,m,:].W_e[c,:] + b[c]
// also accumulates per-channel sum/sumsq partials (1024 blocks x 288 rows)
__global__ __launch_bounds__(256) void k_gate(const float* __restrict__ P, const float* __restrict__ nbrF,
    const int* __restrict__ idx, const float* __restrict__ W, const float* __restrict__ bg,
    bf16* __restrict__ gated, float* __restrict__ psum, float* __restrict__ psq){
  __shared__ float nf[24][44];
  __shared__ int jrow[24];
  __shared__ float red[256];
  int t = threadIdx.x;
  int slot = t >> 7, c = t & 127;
  float wreg[41];
  #pragma unroll
  for (int e = 0; e < 41; e++) wreg[e] = W[(size_t)c*169 + 128 + e];
  float bv = bg[c];
  float s = 0.f, q = 0.f;
  int rbase = blockIdx.x * 288;
  for (int st = 0; st < 12; st++){
    int row0 = rbase + st*24;
    __syncthreads();
    for (int i = t; i < 24*41; i += 256){ int rr = i / 41, e = i - rr*41; nf[rr][e] = nbrF[(size_t)(row0+rr)*41 + e]; }
    if (t < 24) jrow[t] = idx[row0 + t];
    __syncthreads();
    int a = row0/12 + slot;
    float ps = P[(size_t)a*256 + c] + bv;
    #pragma unroll
    for (int m = 0; m < 12; m++){
      int rr = slot*12 + m;
      int j = jrow[rr];
      float acc = ps + P[(size_t)j*256 + 128 + c];
      #pragma unroll
      for (int eb = 0; eb < 10; eb++){
        float4 nv = *(const float4*)&nf[rr][eb*4];
        acc += nv.x*wreg[eb*4] + nv.y*wreg[eb*4+1] + nv.z*wreg[eb*4+2] + nv.w*wreg[eb*4+3];
      }
      acc += nf[rr][40] * wreg[40];
      gated[(size_t)(row0+rr)*128 + c] = f2b(acc);
      s += acc; q += acc*acc;
    }
  }
  red[t] = s; __syncthreads();
  if (t < 128) psum[blockIdx.x*128 + t] = red[t] + red[t+128];
  __syncthreads(); red[t] = q; __syncthreads();
  if (t < 128) psq[blockIdx.x*128 + t] = red[t] + red[t+128];
}

__global__ __launch_bounds__(128) void k_fin1(const float* __restrict__ ps, const float* __restrict__ pq,
    const float* __restrict__ g, const float* __restrict__ be, float* __restrict__ scale, float* __restrict__ shift){
  int c = threadIdx.x;
  float s = 0.f, q = 0.f;
  #pragma unroll 4
  for (int b = 0; b < 1024; b++){ s += ps[b*128 + c]; q += pq[b*128 + c]; }
  float cnt = 294912.0f;
  float mu = s / cnt;
  float var = q / cnt - mu*mu;
  float inv = rsqrtf(var + 1e-5f);
  float sc = inv * g[c];
  scale[c] = sc;
  shift[c] = be[c] - mu * sc;
}

// ---------------- normalize + sigmoid*softplus + sum over M + stats2 ----------------
__global__ __launch_bounds__(256) void k_pool(const bf16* __restrict__ gated, const float* __restrict__ scale,
    const float* __restrict__ shift, float* __restrict__ summed, float* __restrict__ psum, float* __restrict__ psq){
  __shared__ float sc[128], sh[128];
  __shared__ float red[256];
  int t = threadIdx.x;
  if (t < 128){ sc[t] = scale[t]; sh[t] = shift[t]; }
  __syncthreads();
  int d = t & 63, slot = t >> 6;
  float s = 0.f, q = 0.f;
  int abase = blockIdx.x * 24;
  for (int ch = 0; ch < 6; ch++){
    int n = abase + ch*4 + slot;
    const bf16* gp = gated + (size_t)n * 1536;
    float acc = 0.f;
    #pragma unroll
    for (int m = 0; m < 12; m++){
      float y1 = b2f(gp[m*128 + d])      * sc[d]      + sh[d];
      float y2 = b2f(gp[m*128 + 64 + d]) * sc[64 + d] + sh[64 + d];
      acc += sigmoid_f(y1) * softplus_f(y2);
    }
    summed[(size_t)n*64 + d] = acc;
    s += acc; q += acc*acc;
  }
  red[t] = s; __syncthreads();
  if (t < 64) psum[blockIdx.x*64 + t] = red[t] + red[t+64] + red[t+128] + red[t+192];
  __syncthreads(); red[t] = q; __syncthreads();
  if (t < 64) psq[blockIdx.x*64 + t] = red[t] + red[t+64] + red[t+128] + red[t+192];
}

__global__ __launch_bounds__(64) void k_fin2(const float* __restrict__ ps, const float* __restrict__ pq,
    const float* __restrict__ g, const float* __restrict__ be, float* __restrict__ scale, float* __restrict__ shift){
  int c = threadIdx.x;
  float s = 0.f, q = 0.f;
  #pragma unroll 4
  for (int b = 0; b < 1024; b++){ s += ps[b*64 + c]; q += pq[b*64 + c]; }
  float cnt = 24576.0f;
  float mu = s / cnt;
  float var = q / cnt - mu*mu;
  float inv = rsqrtf(var + 1e-5f);
  float sc = inv * g[c];
  scale[c] = sc;
  shift[c] = be[c] - mu * sc;
}

__global__ __launch_bounds__(256) void k_update(const float* __restrict__ fea, const float* __restrict__ summed,
    const float* __restrict__ sc2, const float* __restrict__ sh2, float* __restrict__ out){
  int i = blockIdx.x*256 + threadIdx.x;
  int d = i & 63;
  float x = fea[i] + summed[i]*sc2[d] + sh2[d];
  out[i] = softplus_f(x);
}

// ---------------- decode: per-batch bilinear pair scores + fc + log_softmax + atom head ----------------
__global__ __launch_bounds__(256) void k_decode(const float* __restrict__ fea, const int* __restrict__ cidx,
    const float* __restrict__ Wadj, const float* __restrict__ badj,
    const float* __restrict__ Wfc1, const float* __restrict__ bfc1,
    const float* __restrict__ Wedge, const float* __restrict__ bedge,
    const float* __restrict__ Wfc2, const float* __restrict__ bfc2,
    const float* __restrict__ Watom, const float* __restrict__ batom,
    float* __restrict__ out){
  __shared__ float bt[48][65];
  __shared__ bf16 Ys[6][48][66];
  __shared__ float cst[83]; // fc1[0,36) fb1[36,42) ba[42,48) fc2[48,73) fb2[73,78) be[78,83)
  int t = threadIdx.x, b = blockIdx.x;
  const int* ci = cidx + b*48;
  for (int i = t; i < 3072; i += 256){ int r = i >> 6, d = i & 63; bt[r][d] = fea[(size_t)ci[r]*64 + d]; }
  if (t < 36) cst[t] = Wfc1[t];
  else if (t < 42) cst[t] = bfc1[t-36];
  else if (t < 48) cst[t] = badj[t-42];
  else if (t < 73) cst[t] = Wfc2[t-48];
  else if (t < 78) cst[t] = bfc2[t-73];
  else if (t < 83) cst[t] = bedge[t-78];
  __syncthreads();
  int e = t & 63, slot = t >> 6;

  // Y_k = bt @ W_adj[k]   (contraction over first W dim)
  for (int k = 0; k < 6; k++){
    const float* Wk = Wadj + (size_t)k*4096;
    float acc[12];
    #pragma unroll
    for (int mm = 0; mm < 12; mm++) acc[mm] = 0.f;
    for (int d = 0; d < 64; d++){
      float w = Wk[d*64 + e];
      #pragma unroll
      for (int mm = 0; mm < 12; mm++) acc[mm] += bt[slot + mm*4][d] * w;
    }
    #pragma unroll
    for (int mm = 0; mm < 12; mm++) Ys[k][slot + mm*4][e] = f2b(acc[mm]);
  }
  __syncthreads();

  // edge_p pairs: s_k = Y_k[m,:].bt[n,:] + b_adj; fc1; log_softmax
  size_t obase = (size_t)b * 13824;  // 2304*6
  for (int p = t; p < 2304; p += 256){
    int m = p / 48, n = p - m*48;
    float sv[6];
    #pragma unroll
    for (int k = 0; k < 6; k++){
      float a = 0.f;
      #pragma unroll 8
      for (int ee = 0; ee < 64; ee++) a += b2f(Ys[k][m][ee]) * bt[n][ee];
      sv[k] = a + cst[42 + k];
    }
    float v[6]; float mx = -1e30f;
    #pragma unroll
    for (int i2 = 0; i2 < 6; i2++){
      float a = cst[36 + i2];
      #pragma unroll
      for (int j2 = 0; j2 < 6; j2++) a += cst[i2*6 + j2] * sv[j2];
      v[i2] = a; mx = fmaxf(mx, a);
    }
    float lse = 0.f;
    #pragma unroll
    for (int i2 = 0; i2 < 6; i2++) lse += __expf(v[i2] - mx);
    lse = mx + __logf(lse);
    #pragma unroll
    for (int i2 = 0; i2 < 6; i2++) out[obase + (size_t)p*6 + i2] = v[i2] - lse;
  }
  __syncthreads();

  // Y_k = bt @ W_edge[k]
  for (int k = 0; k < 5; k++){
    const float* Wk = Wedge + (size_t)k*4096;
    float acc[12];
    #pragma unroll
    for (int mm = 0; mm < 12; mm++) acc[mm] = 0.f;
    for (int d = 0; d < 64; d++){
      float w = Wk[d*64 + e];
      #pragma unroll
      for (int mm = 0; mm < 12; mm++) acc[mm] += bt[slot + mm*4][d] * w;
    }
    #pragma unroll
    for (int mm = 0; mm < 12; mm++) Ys[k][slot + mm*4][e] = f2b(acc[mm]);
  }
  __syncthreads();

  // edge_f pairs: fc2, no softmax
  size_t fbase = 9338880ull + (size_t)b * 11520;  // 2304*5
  for (int p = t; p < 2304; p += 256){
    int m = p / 48, n = p - m*48;
    float sv[5];
    #pragma unroll
    for (int k = 0; k < 5; k++){
      float a = 0.f;
      #pragma unroll 8
      for (int ee = 0; ee < 64; ee++) a += b2f(Ys[k][m][ee]) * bt[n][ee];
      sv[k] = a + cst[78 + k];
    }
    #pragma unroll
    for (int i2 = 0; i2 < 5; i2++){
      float a = cst[73 + i2];
      #pragma unroll
      for (int j2 = 0; j2 < 5; j2++) a += cst[48 + i2*5 + j2] * sv[j2];
      out[fbase + (size_t)p*5 + i2] = a;
    }
  }

  // atom_out = bt @ W_atom.T + b_atom
  size_t abase = 7077888ull + (size_t)b * 4416;  // 48*92
  for (int qq = t; qq < 4416; qq += 256){
    int i2 = qq / 92, o = qq - i2*92;
    float a = batom[o];
    #pragma unroll 8
    for (int d = 0; d < 64; d++) a += bt[i2][d] * Watom[o*64 + d];
    out[abase + qq] = a;
  }
}

extern "C" void kernel_launch(void* const* d_in, const int* in_sizes, int n_in,
                              void* d_out, int out_size, void* d_ws, size_t ws_size,
                              hipStream_t stream) {
  const float* atom_fea = (const float*)d_in[0];
  const float* nbr_fea  = (const float*)d_in[1];
  const int*   nbr_idx  = (const int*)d_in[2];
  const int*   cidx     = (const int*)d_in[3];
  const float* W_emb    = (const float*)d_in[4];
  const float* W_full   = (const float*)d_in[5];
  const float* b_full   = (const float*)d_in[6];
  const float* g1       = (const float*)d_in[7];
  const float* be1      = (const float*)d_in[8];
  const float* g2       = (const float*)d_in[9];
  const float* be2      = (const float*)d_in[10];
  const float* W_adj    = (const float*)d_in[11];
  const float* b_adj    = (const float*)d_in[12];
  const float* W_fc1    = (const float*)d_in[13];
  const float* b_fc1    = (const float*)d_in[14];
  const float* W_edge   = (const float*)d_in[15];
  const float* b_edge   = (const float*)d_in[16];
  const float* W_fc2    = (const float*)d_in[17];
  const float* b_fc2    = (const float*)d_in[18];
  const float* W_atom   = (const float*)d_in[19];
  const float* b_atom   = (const float*)d_in[20];

  char* ws = (char*)d_ws;
  float* feaA   = (float*)(ws);                 // 6,291,456 B
  float* feaB   = (float*)(ws + 6291456);       // 6,291,456 B
  float* P      = (float*)(ws + 12582912);      // 25,165,824 B
  float* summed = (float*)(ws + 37748736);      // 6,291,456 B
  float* p1     = (float*)(ws + 44040192);      // 524,288 B
  float* p1q    = (float*)(ws + 44564480);      // 524,288 B
  float* p2     = (float*)(ws + 45088768);      // 262,144 B
  float* p2q    = (float*)(ws + 45350912);      // 262,144 B
  float* sc1    = (float*)(ws + 45613056);      // 512 B
  float* sh1    = (float*)(ws + 45613568);      // 512 B
  float* sc2    = (float*)(ws + 45614080);      // 256 B
  float* sh2    = (float*)(ws + 45614336);      // 256 B
  bf16*  gated  = (bf16*)(ws + 45614592);       // 75,497,472 B (end ~121.1 MB)
  float* out    = (float*)d_out;

  k_embed<<<384, 256, 0, stream>>>(atom_fea, W_emb, feaA);

  float* cur = feaA; float* nxt = feaB;
  for (int l = 0; l < 3; l++){
    const float* Wl = W_full + (size_t)l * 128 * 169;
    k_proj<<<384, 256, 0, stream>>>(cur, Wl, P);
    k_gate<<<1024, 256, 0, stream>>>(P, nbr_fea, nbr_idx, Wl, b_full + l*128, gated, p1, p1q);
    k_fin1<<<1, 128, 0, stream>>>(p1, p1q, g1 + l*128, be1 + l*128, sc1, sh1);
    k_pool<<<1024, 256, 0, stream>>>(gated, sc1, sh1, summed, p2, p2q);
    k_fin2<<<1, 64, 0, stream>>>(p2, p2q, g2 + l*64, be2 + l*64, sc2, sh2);
    k_update<<<6144, 256, 0, stream>>>(cur, summed, sc2, sh2, nxt);
    float* tmp = cur; cur = nxt; nxt = tmp;
  }

  k_decode<<<512, 256, 0, stream>>>(cur, cidx, W_adj, b_adj, W_fc1, b_fc1,
                                    W_edge, b_edge, W_fc2, b_fc2, W_atom, b_atom, out);
}

// Round 3
// 681.403 us; speedup vs baseline: 1.6394x; 1.6394x over previous
//
#include <hip/hip_runtime.h>
#include <hip/hip_bf16.h>

typedef __hip_bfloat16 bf16;
typedef __attribute__((ext_vector_type(8))) short short8v;
typedef __attribute__((ext_vector_type(4))) float f32x4;

__device__ __forceinline__ float b2f(bf16 v){ return __bfloat162float(v); }
__device__ __forceinline__ bf16 f2b(float v){ return __float2bfloat16(v); }
__device__ __forceinline__ float softplus_f(float x){ return (x > 15.f) ? x : __logf(1.f + __expf(x)); }
__device__ __forceinline__ float sigmoid_f(float x){ return 1.f / (1.f + __expf(-x)); }

// ---------------- embedding: fea[n,d] = sum_k A[n,k] * W_emb[d,k] ----------------
__global__ __launch_bounds__(256) void k_embed(const float* __restrict__ A, const float* __restrict__ W,
                                               float* __restrict__ fea){
  __shared__ float Wl[92][64];
  __shared__ float Al[64][92];
  int t = threadIdx.x;
  int base = blockIdx.x * 64;
  for (int i = t; i < 92*64; i += 256){ int d = i / 92, k = i - d*92; Wl[k][d] = W[d*92 + k]; }
  for (int i = t; i < 64*92; i += 256){ int a = i / 92, k = i - a*92; Al[a][k] = A[(size_t)(base+a)*92 + k]; }
  __syncthreads();
  int d = t & 63, slot = t >> 6;
  for (int a = slot; a < 64; a += 4){
    float acc = 0.f;
    #pragma unroll 4
    for (int k = 0; k < 92; k++) acc += Al[a][k] * Wl[k][d];
    fea[(size_t)(base+a)*64 + d] = acc;
  }
}

// ---------------- P[n, c] = fea[n,:] . W_self/W_nbr columns ----------------
__global__ __launch_bounds__(256) void k_proj(const float* __restrict__ fea, const float* __restrict__ W,
                                              float* __restrict__ P){
  __shared__ float Fl[64][64];
  int t = threadIdx.x, base = blockIdx.x * 64;
  int c = t, cc = c & 127;
  const float* wrow = W + (size_t)cc*169 + ((c < 128) ? 0 : 64);
  float wreg[64];
  #pragma unroll
  for (int d = 0; d < 64; d++) wreg[d] = wrow[d];
  for (int i = t; i < 4096; i += 256){ int a = i >> 6, d = i & 63; Fl[a][d] = fea[(size_t)(base+a)*64 + d]; }
  __syncthreads();
  for (int a = 0; a < 64; a++){
    float acc = 0.f;
    #pragma unroll
    for (int db = 0; db < 16; db++){
      float4 fv = *(const float4*)&Fl[a][db*4];
      acc += fv.x*wreg[db*4] + fv.y*wreg[db*4+1] + fv.z*wreg[db*4+2] + fv.w*wreg[db*4+3];
    }
    P[(size_t)(base+a)*256 + c] = acc;
  }
}

// ---------------- gated = P_self + P_nbr[idx] + nbr_fea.W_e + b ; stats partials ----------------
__global__ __launch_bounds__(256) void k_gate(const float* __restrict__ P, const float* __restrict__ nbrF,
    const int* __restrict__ idx, const float* __restrict__ W, const float* __restrict__ bg,
    bf16* __restrict__ gated, float* __restrict__ psum, float* __restrict__ psq){
  __shared__ float nf[24][44];
  __shared__ int jrow[24];
  __shared__ float red[256];
  int t = threadIdx.x;
  int slot = t >> 7, c = t & 127;
  float wreg[41];
  #pragma unroll
  for (int e = 0; e < 41; e++) wreg[e] = W[(size_t)c*169 + 128 + e];
  float bv = bg[c];
  float s = 0.f, q = 0.f;
  int rbase = blockIdx.x * 288;
  for (int st = 0; st < 12; st++){
    int row0 = rbase + st*24;
    __syncthreads();
    for (int i = t; i < 24*41; i += 256){ int rr = i / 41, e = i - rr*41; nf[rr][e] = nbrF[(size_t)(row0+rr)*41 + e]; }
    if (t < 24) jrow[t] = idx[row0 + t];
    __syncthreads();
    int a = row0/12 + slot;
    float ps = P[(size_t)a*256 + c] + bv;
    #pragma unroll
    for (int m = 0; m < 12; m++){
      int rr = slot*12 + m;
      int j = jrow[rr];
      float acc = ps + P[(size_t)j*256 + 128 + c];
      #pragma unroll
      for (int eb = 0; eb < 10; eb++){
        float4 nv = *(const float4*)&nf[rr][eb*4];
        acc += nv.x*wreg[eb*4] + nv.y*wreg[eb*4+1] + nv.z*wreg[eb*4+2] + nv.w*wreg[eb*4+3];
      }
      acc += nf[rr][40] * wreg[40];
      gated[(size_t)(row0+rr)*128 + c] = f2b(acc);
      s += acc; q += acc*acc;
    }
  }
  red[t] = s; __syncthreads();
  if (t < 128) psum[blockIdx.x*128 + t] = red[t] + red[t+128];
  __syncthreads(); red[t] = q; __syncthreads();
  if (t < 128) psq[blockIdx.x*128 + t] = red[t] + red[t+128];
}

__global__ __launch_bounds__(1024) void k_fin1(const float* __restrict__ ps, const float* __restrict__ pq,
    const float* __restrict__ g, const float* __restrict__ be, float* __restrict__ scale, float* __restrict__ shift){
  __shared__ float rs[1024], rq[1024];
  int t = threadIdx.x, c = t & 127, gi = t >> 7;   // 8 groups x 128 channels
  float s = 0.f, q = 0.f;
  for (int b = gi; b < 1024; b += 8){ s += ps[b*128 + c]; q += pq[b*128 + c]; }
  rs[t] = s; rq[t] = q; __syncthreads();
  if (t < 128){
    float S = 0.f, Q = 0.f;
    #pragma unroll
    for (int gg = 0; gg < 8; gg++){ S += rs[gg*128 + t]; Q += rq[gg*128 + t]; }
    float cnt = 294912.0f;
    float mu = S / cnt;
    float var = Q / cnt - mu*mu;
    float sc = rsqrtf(var + 1e-5f) * g[t];
    scale[t] = sc;
    shift[t] = be[t] - mu * sc;
  }
}

// ---------------- normalize + sigmoid*softplus + sum over M + stats2 ----------------
__global__ __launch_bounds__(256) void k_pool(const bf16* __restrict__ gated, const float* __restrict__ scale,
    const float* __restrict__ shift, float* __restrict__ summed, float* __restrict__ psum, float* __restrict__ psq){
  __shared__ float sc[128], sh[128];
  __shared__ float red[256];
  int t = threadIdx.x;
  if (t < 128){ sc[t] = scale[t]; sh[t] = shift[t]; }
  __syncthreads();
  int d = t & 63, slot = t >> 6;
  float s = 0.f, q = 0.f;
  int abase = blockIdx.x * 24;
  for (int ch = 0; ch < 6; ch++){
    int n = abase + ch*4 + slot;
    const bf16* gp = gated + (size_t)n * 1536;
    float acc = 0.f;
    #pragma unroll
    for (int m = 0; m < 12; m++){
      float y1 = b2f(gp[m*128 + d])      * sc[d]      + sh[d];
      float y2 = b2f(gp[m*128 + 64 + d]) * sc[64 + d] + sh[64 + d];
      acc += sigmoid_f(y1) * softplus_f(y2);
    }
    summed[(size_t)n*64 + d] = acc;
    s += acc; q += acc*acc;
  }
  red[t] = s; __syncthreads();
  if (t < 64) psum[blockIdx.x*64 + t] = red[t] + red[t+64] + red[t+128] + red[t+192];
  __syncthreads(); red[t] = q; __syncthreads();
  if (t < 64) psq[blockIdx.x*64 + t] = red[t] + red[t+64] + red[t+128] + red[t+192];
}

__global__ __launch_bounds__(1024) void k_fin2(const float* __restrict__ ps, const float* __restrict__ pq,
    const float* __restrict__ g, const float* __restrict__ be, float* __restrict__ scale, float* __restrict__ shift){
  __shared__ float rs[1024], rq[1024];
  int t = threadIdx.x, c = t & 63, gi = t >> 6;   // 16 groups x 64 channels
  float s = 0.f, q = 0.f;
  for (int b = gi; b < 1024; b += 16){ s += ps[b*64 + c]; q += pq[b*64 + c]; }
  rs[t] = s; rq[t] = q; __syncthreads();
  if (t < 64){
    float S = 0.f, Q = 0.f;
    #pragma unroll
    for (int gg = 0; gg < 16; gg++){ S += rs[gg*64 + t]; Q += rq[gg*64 + t]; }
    float cnt = 24576.0f;
    float mu = S / cnt;
    float var = Q / cnt - mu*mu;
    float sc = rsqrtf(var + 1e-5f) * g[t];
    scale[t] = sc;
    shift[t] = be[t] - mu * sc;
  }
}

__global__ __launch_bounds__(256) void k_update(const float* __restrict__ fea, const float* __restrict__ summed,
    const float* __restrict__ sc2, const float* __restrict__ sh2, float* __restrict__ out){
  int i = blockIdx.x*256 + threadIdx.x;
  int d = i & 63;
  float x = fea[i] + summed[i]*sc2[d] + sh2[d];
  out[i] = softplus_f(x);
}

// ================= MFMA decode =================
// Per block b: bt[48][64]. For each head k: Z_k = W_k @ bt^T (64x48), s_k = bt @ Z_k (48x48).
// All MFMA operands are 8-contiguous-k row-major LDS reads (ds_read_b128). Rows padded to 72
// bf16 (144 B) -> <=2-way bank aliasing (free).
template<int KN>
__device__ __forceinline__ void pair_phase(const float* __restrict__ Wbase,
    bf16 (*__restrict__ btb)[72], bf16 (*__restrict__ sbuf)[72],
    int t, int lane, int w, f32x4 acc[3][6]){
  #pragma unroll
  for (int i = 0; i < 3; i++)
    #pragma unroll
    for (int k = 0; k < KN; k++) acc[i][k] = (f32x4){0.f,0.f,0.f,0.f};
  #pragma unroll
  for (int k = 0; k < KN; k++){
    const float* Wk = Wbase + (size_t)k*4096;
    __syncthreads();                       // protect Wd/Zt from previous iteration readers
    for (int i = t; i < 4096; i += 256) sbuf[i>>6][i&63] = f2b(Wk[i]);   // Wd[d][e]
    __syncthreads();
    // Z GEMM: wave w owns d-block w (d0 = 16w); Z[d][n] -> stored transposed Zt[n][d] at sbuf[64+n]
    #pragma unroll
    for (int nc = 0; nc < 3; nc++){
      f32x4 z = (f32x4){0.f,0.f,0.f,0.f};
      #pragma unroll
      for (int ec = 0; ec < 64; ec += 32){
        short8v av = *(const short8v*)&sbuf[w*16 + (lane&15)][ec + (lane>>4)*8];
        short8v bv = *(const short8v*)&btb [nc*16 + (lane&15)][ec + (lane>>4)*8];
        z = __builtin_amdgcn_mfma_f32_16x16x32_bf16(av, bv, z, 0, 0, 0);
      }
      bf16 zp[4];
      #pragma unroll
      for (int r = 0; r < 4; r++) zp[r] = f2b(z[r]);
      // n = nc*16+(lane&15), d = 16w + (lane>>4)*4 + r : 4 consecutive bf16 -> one 8B store
      *(uint2*)&sbuf[64 + nc*16 + (lane&15)][w*16 + (lane>>4)*4] = *(const uint2*)zp;
    }
    __syncthreads();
    // s GEMM: tiles tid = w, w+4, w+8 over 3x3 grid; accumulate into regs
    #pragma unroll
    for (int i = 0; i < 3; i++){
      int tid = w + 4*i;
      if (tid < 9){
        int mr = tid / 3, nc = tid - mr*3;
        #pragma unroll
        for (int dc = 0; dc < 64; dc += 32){
          short8v av = *(const short8v*)&btb [mr*16 + (lane&15)][dc + (lane>>4)*8];
          short8v bv = *(const short8v*)&sbuf[64 + nc*16 + (lane&15)][dc + (lane>>4)*8];
          acc[i][k] = __builtin_amdgcn_mfma_f32_16x16x32_bf16(av, bv, acc[i][k], 0, 0, 0);
        }
      }
    }
  }
}

__global__ __launch_bounds__(256) void k_decode(const float* __restrict__ fea, const int* __restrict__ cidx,
    const float* __restrict__ Wadj, const float* __restrict__ badj,
    const float* __restrict__ Wfc1, const float* __restrict__ bfc1,
    const float* __restrict__ Wedge, const float* __restrict__ bedge,
    const float* __restrict__ Wfc2, const float* __restrict__ bfc2,
    const float* __restrict__ Watom, const float* __restrict__ batom,
    float* __restrict__ out){
  __shared__ bf16 btb[48][72];
  __shared__ bf16 sbuf[112][72];   // Wd rows 0..63, Zt rows 64..111; atom phase: Wab rows 0..95
  __shared__ float cst[84];        // fc1[0,36) fb1[36,42) ba[42,48) fc2[48,73) fb2[73,78) be[78,83)
  __shared__ float ba2[92];
  int t = threadIdx.x, b = blockIdx.x;
  int lane = t & 63, w = t >> 6;
  const int* ci = cidx + b*48;
  for (int i = t; i < 48*64; i += 256){ int r = i>>6, d = i&63; btb[r][d] = f2b(fea[(size_t)ci[r]*64 + d]); }
  if (t < 36) cst[t] = Wfc1[t];
  else if (t < 42) cst[t] = bfc1[t-36];
  else if (t < 48) cst[t] = badj[t-42];
  else if (t < 73) cst[t] = Wfc2[t-48];
  else if (t < 78) cst[t] = bfc2[t-73];
  else if (t < 83) cst[t] = bedge[t-78];
  if (t >= 128 && t < 220) ba2[t-128] = batom[t-128];

  f32x4 acc[3][6];

  // ---- edge_p: 6 bilinear heads + fc1 + log_softmax ----
  pair_phase<6>(Wadj, btb, sbuf, t, lane, w, acc);
  size_t obase = (size_t)b * 13824;
  #pragma unroll
  for (int i = 0; i < 3; i++){
    int tid = w + 4*i;
    if (tid < 9){
      int mr = tid / 3, nc = tid - mr*3;
      #pragma unroll
      for (int r = 0; r < 4; r++){
        int m = mr*16 + (lane>>4)*4 + r;
        int n = nc*16 + (lane&15);
        float sv[6];
        #pragma unroll
        for (int k = 0; k < 6; k++) sv[k] = acc[i][k][r] + cst[42+k];
        float v[6]; float mx = -1e30f;
        #pragma unroll
        for (int i2 = 0; i2 < 6; i2++){
          float a = cst[36+i2];
          #pragma unroll
          for (int j2 = 0; j2 < 6; j2++) a += cst[i2*6+j2] * sv[j2];
          v[i2] = a; mx = fmaxf(mx, a);
        }
        float lse = 0.f;
        #pragma unroll
        for (int i2 = 0; i2 < 6; i2++) lse += __expf(v[i2] - mx);
        lse = mx + __logf(lse);
        size_t po = obase + (size_t)(m*48 + n)*6;
        #pragma unroll
        for (int i2 = 0; i2 < 6; i2++) out[po + i2] = v[i2] - lse;
      }
    }
  }

  // ---- edge_f: 5 bilinear heads + fc2 ----
  pair_phase<5>(Wedge, btb, sbuf, t, lane, w, acc);
  size_t fbase = 9338880ull + (size_t)b * 11520;
  #pragma unroll
  for (int i = 0; i < 3; i++){
    int tid = w + 4*i;
    if (tid < 9){
      int mr = tid / 3, nc = tid - mr*3;
      #pragma unroll
      for (int r = 0; r < 4; r++){
        int m = mr*16 + (lane>>4)*4 + r;
        int n = nc*16 + (lane&15);
        float sv[5];
        #pragma unroll
        for (int k = 0; k < 5; k++) sv[k] = acc[i][k][r] + cst[78+k];
        size_t po = fbase + (size_t)(m*48 + n)*5;
        #pragma unroll
        for (int i2 = 0; i2 < 5; i2++){
          float a = cst[73+i2];
          #pragma unroll
          for (int j2 = 0; j2 < 5; j2++) a += cst[48 + i2*5 + j2] * sv[j2];
          out[po + i2] = a;
        }
      }
    }
  }

  // ---- atom head: bt @ W_atom^T (48x92) ----
  __syncthreads();
  for (int i = t; i < 96*64; i += 256){ int o = i>>6, d = i&63; sbuf[o][d] = (o < 92) ? f2b(Watom[i]) : f2b(0.f); }
  __syncthreads();
  size_t abase = 7077888ull + (size_t)b * 4416;
  #pragma unroll
  for (int i = 0; i < 5; i++){
    int tid = w + 4*i;
    if (tid < 18){
      int mr = tid / 6, oc = tid - mr*6;
      f32x4 a = (f32x4){0.f,0.f,0.f,0.f};
      #pragma unroll
      for (int dc = 0; dc < 64; dc += 32){
        short8v av = *(const short8v*)&btb [mr*16 + (lane&15)][dc + (lane>>4)*8];
        short8v bv = *(const short8v*)&sbuf[oc*16 + (lane&15)][dc + (lane>>4)*8];
        a = __builtin_amdgcn_mfma_f32_16x16x32_bf16(av, bv, a, 0, 0, 0);
      }
      int o = oc*16 + (lane&15);
      if (o < 92){
        float bb = ba2[o];
        #pragma unroll
        for (int r = 0; r < 4; r++){
          int m = mr*16 + (lane>>4)*4 + r;
          out[abase + (size_t)m*92 + o] = a[r] + bb;
        }
      }
    }
  }
}

extern "C" void kernel_launch(void* const* d_in, const int* in_sizes, int n_in,
                              void* d_out, int out_size, void* d_ws, size_t ws_size,
                              hipStream_t stream) {
  const float* atom_fea = (const float*)d_in[0];
  const float* nbr_fea  = (const float*)d_in[1];
  const int*   nbr_idx  = (const int*)d_in[2];
  const int*   cidx     = (const int*)d_in[3];
  const float* W_emb    = (const float*)d_in[4];
  const float* W_full   = (const float*)d_in[5];
  const float* b_full   = (const float*)d_in[6];
  const float* g1       = (const float*)d_in[7];
  const float* be1      = (const float*)d_in[8];
  const float* g2       = (const float*)d_in[9];
  const float* be2      = (const float*)d_in[10];
  const float* W_adj    = (const float*)d_in[11];
  const float* b_adj    = (const float*)d_in[12];
  const float* W_fc1    = (const float*)d_in[13];
  const float* b_fc1    = (const float*)d_in[14];
  const float* W_edge   = (const float*)d_in[15];
  const float* b_edge   = (const float*)d_in[16];
  const float* W_fc2    = (const float*)d_in[17];
  const float* b_fc2    = (const float*)d_in[18];
  const float* W_atom   = (const float*)d_in[19];
  const float* b_atom   = (const float*)d_in[20];

  char* ws = (char*)d_ws;
  float* feaA   = (float*)(ws);
  float* feaB   = (float*)(ws + 6291456);
  float* P      = (float*)(ws + 12582912);
  float* summed = (float*)(ws + 37748736);
  float* p1     = (float*)(ws + 44040192);
  float* p1q    = (float*)(ws + 44564480);
  float* p2     = (float*)(ws + 45088768);
  float* p2q    = (float*)(ws + 45350912);
  float* sc1    = (float*)(ws + 45613056);
  float* sh1    = (float*)(ws + 45613568);
  float* sc2    = (float*)(ws + 45614080);
  float* sh2    = (float*)(ws + 45614336);
  bf16*  gated  = (bf16*)(ws + 45614592);
  float* out    = (float*)d_out;

  k_embed<<<384, 256, 0, stream>>>(atom_fea, W_emb, feaA);

  float* cur = feaA; float* nxt = feaB;
  for (int l = 0; l < 3; l++){
    const float* Wl = W_full + (size_t)l * 128 * 169;
    k_proj<<<384, 256, 0, stream>>>(cur, Wl, P);
    k_gate<<<1024, 256, 0, stream>>>(P, nbr_fea, nbr_idx, Wl, b_full + l*128, gated, p1, p1q);
    k_fin1<<<1, 1024, 0, stream>>>(p1, p1q, g1 + l*128, be1 + l*128, sc1, sh1);
    k_pool<<<1024, 256, 0, stream>>>(gated, sc1, sh1, summed, p2, p2q);
    k_fin2<<<1, 1024, 0, stream>>>(p2, p2q, g2 + l*64, be2 + l*64, sc2, sh2);
    k_update<<<6144, 256, 0, stream>>>(cur, summed, sc2, sh2, nxt);
    float* tmp = cur; cur = nxt; nxt = tmp;
  }

  k_decode<<<512, 256, 0, stream>>>(cur, cidx, W_adj, b_adj, W_fc1, b_fc1,
                                    W_edge, b_edge, W_fc2, b_fc2, W_atom, b_atom, out);
}